// Round 19
// baseline (290.705 us; speedup 1.0000x reference)
//
#include <hip/hip_runtime.h>
#include <hip/hip_bf16.h>
#include <math.h>

#define VOCAB 32000
#define EMB   256
#define TSEQ  1024
#define NROWS 4096

typedef __attribute__((ext_vector_type(8))) short short8;
typedef __attribute__((ext_vector_type(4))) float f32x4;

static __device__ __forceinline__ unsigned short bfb(float x) {
    __hip_bfloat16 h = __float2bfloat16(x);
    return *(unsigned short*)&h;
}
static __device__ __forceinline__ unsigned pk2(float a, float b) {
    return (unsigned)bfb(a) | ((unsigned)bfb(b) << 16);
}

// ---------------- pre-pass: Wq/Wk/Wv transpose+convert (bx<192), embed (bx>=192) ----------------
__global__ __launch_bounds__(256) void k_pre(const float* __restrict__ Wq,
                                             const float* __restrict__ Wk,
                                             const float* __restrict__ Wv,
                                             const int* __restrict__ idx,
                                             const float* __restrict__ tok,
                                             const float* __restrict__ pos,
                                             ushort* __restrict__ Wt3,
                                             ushort* __restrict__ xb) {
    int bx = blockIdx.x;
    if (bx >= 192) {                       // embed
        int row = bx - 192;
        int t = row & (TSEQ - 1);
        int token = idx[row];
        int e = threadIdx.x;
        xb[row * EMB + e] = bfb(tok[token * EMB + e] + pos[t * EMB + e]);
        return;
    }
    __shared__ float T[32][33];
    int z = bx >> 6, rem = bx & 63;
    const float* W = (z == 0) ? Wq : (z == 1) ? Wk : Wv;
    ushort* out = Wt3 + (size_t)z * EMB * EMB;
    int n0 = (rem >> 3) * 32, k0 = (rem & 7) * 32;
    int tx = threadIdx.x & 31, ty = threadIdx.x >> 5;
    #pragma unroll
    for (int i = 0; i < 4; ++i) {
        int kk = ty + 8 * i;
        T[kk][tx] = W[(size_t)(k0 + kk) * EMB + n0 + tx];
    }
    __syncthreads();
    #pragma unroll
    for (int i = 0; i < 4; ++i) {
        int r = ty + 8 * i;
        out[(size_t)(n0 + r) * EMB + k0 + tx] = bfb(T[tx][r]);
    }
}

// ---------------- qkv MFMA GEMM (unchanged) ----------------
__global__ __launch_bounds__(256) void k_qkv_mm(const ushort* __restrict__ A,
                                                const ushort* __restrict__ Wt3,
                                                ushort* __restrict__ qb,
                                                ushort* __restrict__ kbf,
                                                ushort* __restrict__ vt) {
    __shared__ ushort As[128 * 64];
    __shared__ ushort Bs[128 * 64];

    int z = blockIdx.z;
    const ushort* Bt = Wt3 + (size_t)z * EMB * EMB;

    int m0 = blockIdx.x * 128, n0 = blockIdx.y * 128;
    int tid = threadIdx.x;
    int lane = tid & 63, wave = tid >> 6;
    int wm = wave >> 1, wn = wave & 1;
    int lr = lane >> 3, cc = lane & 7;
    int lrow = lane & 15, lk = lane >> 4;

    f32x4 acc[4][4];
    #pragma unroll
    for (int i = 0; i < 4; ++i)
        #pragma unroll
        for (int j = 0; j < 4; ++j)
            acc[i][j] = (f32x4){0.f, 0.f, 0.f, 0.f};

    for (int k0 = 0; k0 < EMB; k0 += 64) {
        #pragma unroll
        for (int j = 0; j < 4; ++j) {
            int rbase = j * 32 + wave * 8;
            int row = rbase + lr;
            int cs = cc ^ (row & 7);
            const ushort* ga = A + (size_t)(m0 + row) * EMB + k0 + cs * 8;
            const ushort* gb = Bt + (size_t)(n0 + row) * EMB + k0 + cs * 8;
            __builtin_amdgcn_global_load_lds(
                (const __attribute__((address_space(1))) void*)ga,
                (__attribute__((address_space(3))) void*)&As[rbase * 64], 16, 0, 0);
            __builtin_amdgcn_global_load_lds(
                (const __attribute__((address_space(1))) void*)gb,
                (__attribute__((address_space(3))) void*)&Bs[rbase * 64], 16, 0, 0);
        }
        __syncthreads();
        #pragma unroll
        for (int kk = 0; kk < 2; ++kk) {
            short8 a[4], b[4];
            #pragma unroll
            for (int m = 0; m < 4; ++m) {
                int row = wm * 64 + m * 16 + lrow;
                int c2 = (kk * 4 + lk) ^ (row & 7);
                a[m] = *(const short8*)&As[row * 64 + c2 * 8];
            }
            #pragma unroll
            for (int n = 0; n < 4; ++n) {
                int row = wn * 64 + n * 16 + lrow;
                int c2 = (kk * 4 + lk) ^ (row & 7);
                b[n] = *(const short8*)&Bs[row * 64 + c2 * 8];
            }
            if (z < 2) {
                #pragma unroll
                for (int m = 0; m < 4; ++m)
                    #pragma unroll
                    for (int n = 0; n < 4; ++n)
                        acc[m][n] = __builtin_amdgcn_mfma_f32_16x16x32_bf16(
                            b[n], a[m], acc[m][n], 0, 0, 0);   // swapped
            } else {
                #pragma unroll
                for (int m = 0; m < 4; ++m)
                    #pragma unroll
                    for (int n = 0; n < 4; ++n)
                        acc[m][n] = __builtin_amdgcn_mfma_f32_16x16x32_bf16(
                            a[m], b[n], acc[m][n], 0, 0, 0);
            }
        }
        __syncthreads();
    }

    if (z < 2) {
        ushort* out = (z == 0) ? qb : kbf;
        #pragma unroll
        for (int m = 0; m < 4; ++m) {
            int token = m0 + wm * 64 + m * 16 + lrow;
            #pragma unroll
            for (int n = 0; n < 4; ++n) {
                uint2 w;
                w.x = pk2(acc[m][n][0], acc[m][n][1]);
                w.y = pk2(acc[m][n][2], acc[m][n][3]);
                *(uint2*)&out[(size_t)token * EMB + n0 + wn * 64 + n * 16 + lk * 4] = w;
            }
        }
    } else {
        #pragma unroll
        for (int n = 0; n < 4; ++n) {
            int e = n0 + wn * 64 + n * 16 + lrow;
            #pragma unroll
            for (int m = 0; m < 4; ++m) {
                int row = m0 + wm * 64 + m * 16 + lk * 4;
                int bb = row >> 10, rr = row & 1023;
                uint2 w;
                w.x = pk2(acc[m][n][0], acc[m][n][1]);
                w.y = pk2(acc[m][n][2], acc[m][n][3]);
                *(uint2*)&vt[((size_t)bb * EMB + e) * TSEQ + rr] = w;
            }
        }
    }
}

// ---------------- merged: flash attention (blocks 0..31) || lm_W transpose (blocks 32..4031) ----------------
__global__ __launch_bounds__(512) void k_attn_conv(const ushort* __restrict__ qg,
                                                   const ushort* __restrict__ kg,
                                                   const ushort* __restrict__ vt,
                                                   ushort* __restrict__ ao,
                                                   const float* __restrict__ lmW,
                                                   ushort* __restrict__ Wt) {
    __shared__ ushort K_s[2][32 * 256];
    __shared__ ushort V_s[2][256 * 32];

    if (blockIdx.x >= 32) {
        int t = threadIdx.x & 255;
        int half = threadIdx.x >> 8;
        int tile = (blockIdx.x - 32) * 2 + half;
        int n0 = (tile >> 3) * 32, k0 = (tile & 7) * 32;
        float* T = (float*)&K_s[0][0] + half * (32 * 33);
        int tx = t & 31, ty = t >> 5;
        #pragma unroll
        for (int i = 0; i < 4; ++i) {
            int kk = ty + 8 * i;
            T[kk * 33 + tx] = lmW[(size_t)(k0 + kk) * VOCAB + n0 + tx];
        }
        __syncthreads();
        #pragma unroll
        for (int i = 0; i < 4; ++i) {
            int r = ty + 8 * i;
            Wt[(size_t)(n0 + r) * EMB + k0 + tx] = bfb(T[tx * 33 + r]);
        }
        return;
    }

    int b = blockIdx.x >> 3;
    int g = blockIdx.x & 7;
    int wave = threadIdx.x >> 6;
    int lane = threadIdx.x & 63;
    int qbase = g * 128 + wave * 16;
    int q = lane & 15, lk = lane >> 4;

    const ushort* qrow = qg + (size_t)(b * TSEQ + qbase + q) * EMB;
    short8 qf[8];
    #pragma unroll
    for (int c = 0; c < 8; ++c)
        qf[c] = *(const short8*)&qrow[c * 32 + lk * 8];

    f32x4 o[16];
    #pragma unroll
    for (int i = 0; i < 16; ++i) o[i] = (f32x4){0.f, 0.f, 0.f, 0.f};
    float m_run = -1e30f, l_run = 0.f;

    auto STAGE = [&](int buf, int st) {
        const ushort* kbase = kg + (size_t)(b * TSEQ + st * 32) * EMB;
        #pragma unroll
        for (int i = 0; i < 2; ++i) {
            int t = wave * 2 + i;
            int r = t * 2 + (lane >> 5);
            int slot = lane & 31;
            int chunk = slot ^ (r & 7);
            const ushort* src = kbase + r * EMB + chunk * 8;
            __builtin_amdgcn_global_load_lds(
                (const __attribute__((address_space(1))) void*)src,
                (__attribute__((address_space(3))) void*)&K_s[buf][t * 512], 16, 0, 0);
        }
        #pragma unroll
        for (int i = 0; i < 2; ++i) {
            int t = wave * 2 + i;
            int e = t * 16 + (lane >> 2);
            int slot = lane & 3;
            int chunk = slot ^ (e & 3);
            const ushort* src = vt + ((size_t)b * EMB + e) * TSEQ + st * 32 + chunk * 8;
            __builtin_amdgcn_global_load_lds(
                (const __attribute__((address_space(1))) void*)src,
                (__attribute__((address_space(3))) void*)&V_s[buf][t * 512], 16, 0, 0);
        }
    };

    int wlast = (qbase + 15) >> 5;
    int glast = (g * 128 + 127) >> 5;
    STAGE(0, 0);
    int buf = 0;

    for (int st = 0; st <= glast; ++st) {
        if (st < glast) {
            STAGE(buf ^ 1, st + 1);
            asm volatile("s_waitcnt vmcnt(4)" ::: "memory");
        } else {
            asm volatile("s_waitcnt vmcnt(0)" ::: "memory");
        }
        __builtin_amdgcn_s_barrier();

        if (st <= wlast) {
            f32x4 sa0 = (f32x4){0.f, 0.f, 0.f, 0.f};
            f32x4 sa1 = (f32x4){0.f, 0.f, 0.f, 0.f};
            #pragma unroll
            for (int c = 0; c < 8; ++c) {
                int sl = (c * 4 + lk) ^ (q & 7);
                short8 kf0 = *(const short8*)&K_s[buf][q * 256 + sl * 8];
                short8 kf1 = *(const short8*)&K_s[buf][(16 + q) * 256 + sl * 8];
                sa0 = __builtin_amdgcn_mfma_f32_16x16x32_bf16(kf0, qf[c], sa0, 0, 0, 0);
                sa1 = __builtin_amdgcn_mfma_f32_16x16x32_bf16(kf1, qf[c], sa1, 0, 0, 0);
            }

            float sv0[4], sv1[4];
            #pragma unroll
            for (int j = 0; j < 4; ++j) { sv0[j] = sa0[j] * 0.0625f; sv1[j] = sa1[j] * 0.0625f; }
            if (st == wlast) {
                int qgl = qbase + q;
                #pragma unroll
                for (int j = 0; j < 4; ++j) {
                    if (st * 32 + lk * 4 + j > qgl)      sv0[j] = -1e30f;
                    if (st * 32 + 16 + lk * 4 + j > qgl) sv1[j] = -1e30f;
                }
            }

            float tm = sv0[0];
            #pragma unroll
            for (int j = 1; j < 4; ++j) tm = fmaxf(tm, sv0[j]);
            #pragma unroll
            for (int j = 0; j < 4; ++j) tm = fmaxf(tm, sv1[j]);
            tm = fmaxf(tm, __shfl_xor(tm, 16));
            tm = fmaxf(tm, __shfl_xor(tm, 32));
            float mn = fmaxf(m_run, tm);
            float alpha = __expf(m_run - mn);
            float p0[4], p1[4], ts = 0.f;
            #pragma unroll
            for (int j = 0; j < 4; ++j) {
                p0[j] = __expf(sv0[j] - mn);
                p1[j] = __expf(sv1[j] - mn);
                ts += p0[j] + p1[j];
            }
            ts += __shfl_xor(ts, 16);
            ts += __shfl_xor(ts, 32);
            l_run = l_run * alpha + ts;
            m_run = mn;

            #pragma unroll
            for (int i = 0; i < 16; ++i) {
                o[i][0] *= alpha; o[i][1] *= alpha; o[i][2] *= alpha; o[i][3] *= alpha;
            }

            unsigned c0 = pk2(p0[0], p0[1]), c1 = pk2(p0[2], p0[3]);
            unsigned d0 = pk2(p1[0], p1[1]), d1 = pk2(p1[2], p1[3]);
            int sA = q + 32 * (lk & 1);
            int sB = sA + 16;
            unsigned a0c = __shfl(c0, sA), a1c = __shfl(c1, sA);
            unsigned b0c = __shfl(c0, sB), b1c = __shfl(c1, sB);
            unsigned a0d = __shfl(d0, sA), a1d = __shfl(d1, sA);
            unsigned b0d = __shfl(d0, sB), b1d = __shfl(d1, sB);
            bool hi = (lk >> 1) != 0;
            union { short8 s; unsigned u[4]; } pb;
            pb.u[0] = hi ? a0d : a0c;
            pb.u[1] = hi ? a1d : a1c;
            pb.u[2] = hi ? b0d : b0c;
            pb.u[3] = hi ? b1d : b1c;

            #pragma unroll
            for (int eb = 0; eb < 16; ++eb) {
                int er = eb * 16 + q;
                int sl = lk ^ (er & 3);
                short8 vf = *(const short8*)&V_s[buf][er * 32 + sl * 8];
                o[eb] = __builtin_amdgcn_mfma_f32_16x16x32_bf16(vf, pb.s, o[eb], 0, 0, 0);
            }
        }
        __builtin_amdgcn_s_barrier();
        buf ^= 1;
    }

    float inv_l = 1.f / l_run;
    ushort* orow = ao + (size_t)(b * TSEQ + qbase + q) * EMB;
    #pragma unroll
    for (int eb = 0; eb < 16; ++eb) {
        uint2 w;
        w.x = pk2(o[eb][0] * inv_l, o[eb][1] * inv_l);
        w.y = pk2(o[eb][2] * inv_l, o[eb][3] * inv_l);
        *(uint2*)&orow[eb * 16 + lk * 4] = w;
    }
}

// ---------------- logits GEMM: R18 + nb-inner block mapping (adjacent-column concurrency) ----------------
__global__ __launch_bounds__(256) void k_gemm(const ushort* __restrict__ A,
                                              const ushort* __restrict__ Bt,
                                              const float* __restrict__ lmb,
                                              float* __restrict__ C,
                                              float* __restrict__ rowsum) {
    __shared__ ushort SH[4 * 128 * 64];   // 64 KB: As[0],As[1],Bs[0],Bs[1]; reused as C-tile

    int linear = blockIdx.x;
    int swz = (linear & 7) * 1000 + (linear >> 3);   // bijective XCD swizzle (8000%8==0)
    int nb = swz % 250;                               // nb INNER: concurrent blocks on an XCD
    int m0 = (swz / 250) * 128;                       // write adjacent 512B column segments
    int n0 = nb * 128;

    int tid = threadIdx.x;
    int lane = tid & 63, wave = tid >> 6;
    int wm = wave >> 1, wn = wave & 1;
    int lr = lane >> 3, cc = lane & 7;
    int lrow = lane & 15, lk = lane >> 4;

    auto STAGE = [&](int bufi, int k0) {
        ushort* Asb = &SH[bufi * 8192];
        ushort* Bsb = &SH[16384 + bufi * 8192];
        #pragma unroll
        for (int j = 0; j < 4; ++j) {
            int rbase = j * 32 + wave * 8;
            int row = rbase + lr;
            int cs = cc ^ (row & 7);
            const ushort* ga = A + (size_t)(m0 + row) * EMB + k0 + cs * 8;
            const ushort* gb = Bt + (size_t)(n0 + row) * EMB + k0 + cs * 8;
            __builtin_amdgcn_global_load_lds(
                (const __attribute__((address_space(1))) void*)ga,
                (__attribute__((address_space(3))) void*)&Asb[rbase * 64], 16, 0, 0);
            __builtin_amdgcn_global_load_lds(
                (const __attribute__((address_space(1))) void*)gb,
                (__attribute__((address_space(3))) void*)&Bsb[rbase * 64], 16, 0, 0);
        }
    };

    f32x4 acc[4][4];
    #pragma unroll
    for (int i = 0; i < 4; ++i)
        #pragma unroll
        for (int j = 0; j < 4; ++j)
            acc[i][j] = (f32x4){0.f, 0.f, 0.f, 0.f};

    STAGE(0, 0);
    asm volatile("s_waitcnt vmcnt(0)" ::: "memory");
    __syncthreads();

    #pragma unroll
    for (int t = 0; t < 4; ++t) {
        if (t < 3) STAGE((t + 1) & 1, (t + 1) * 64);   // prefetch next, in flight under compute
        const ushort* Ab = &SH[(t & 1) * 8192];
        const ushort* Bb = &SH[16384 + (t & 1) * 8192];
        #pragma unroll
        for (int kk = 0; kk < 2; ++kk) {
            short8 a[4], b[4];
            #pragma unroll
            for (int m = 0; m < 4; ++m) {
                int row = wm * 64 + m * 16 + lrow;
                int c2 = (kk * 4 + lk) ^ (row & 7);
                a[m] = *(const short8*)&Ab[row * 64 + c2 * 8];
            }
            #pragma unroll
            for (int n = 0; n < 4; ++n) {
                int row = wn * 64 + n * 16 + lrow;
                int c2 = (kk * 4 + lk) ^ (row & 7);
                b[n] = *(const short8*)&Bb[row * 64 + c2 * 8];
            }
            #pragma unroll
            for (int m = 0; m < 4; ++m)
                #pragma unroll
                for (int n = 0; n < 4; ++n)
                    acc[m][n] = __builtin_amdgcn_mfma_f32_16x16x32_bf16(
                        b[n], a[m], acc[m][n], 0, 0, 0);   // SWAPPED
        }
        if (t < 3) {
            asm volatile("s_waitcnt vmcnt(0)" ::: "memory");
            __syncthreads();
        }
    }

    // bias: 4 consecutive vocab cols per lane per n
    f32x4 bias4[4];
    #pragma unroll
    for (int n = 0; n < 4; ++n)
        bias4[n] = *(const f32x4*)&lmb[n0 + wn * 64 + n * 16 + lk * 4];

    // per-token sum-exp over this wn-half's 64 cols -> atomic into L2-resident rowsum
    #pragma unroll
    for (int m = 0; m < 4; ++m) {
        float tS = 0.f;
        #pragma unroll
        for (int n = 0; n < 4; ++n)
            #pragma unroll
            for (int j = 0; j < 4; ++j)
                tS += __expf(acc[m][n][j] + bias4[n][j]);
        tS += __shfl_xor(tS, 16);
        tS += __shfl_xor(tS, 32);
        if (lk == 0)
            atomicAdd(&rowsum[m0 + wm * 64 + m * 16 + lrow], tS);
    }

    // ---- LDS-coalesced C write ----
    __syncthreads();                      // all waves done reading As/Bs for MFMA
    f32x4* Cs4 = (f32x4*)SH;              // 128 tokens x 32 chunks (16B each)
    #pragma unroll
    for (int m = 0; m < 4; ++m) {
        int ltok = wm * 64 + m * 16 + lrow;
        #pragma unroll
        for (int n = 0; n < 4; ++n) {
            int cq = wn * 16 + n * 4 + lk;
            Cs4[ltok * 32 + (cq ^ ((ltok & 7) << 2))] = acc[m][n] + bias4[n];
        }
    }
    __syncthreads();                      // C-tile complete
    int lt_base = tid >> 5;
    int cq_out = tid & 31;
    #pragma unroll
    for (int it = 0; it < 16; ++it) {
        int lt = it * 8 + lt_base;
        f32x4 v = Cs4[lt * 32 + (cq_out ^ ((lt & 7) << 2))];
        __builtin_nontemporal_store(v,
            (f32x4*)&C[(size_t)(m0 + lt) * VOCAB + n0 + cq_out * 4]);
    }
}

// ---------------- loss: 16 blocks, log(rowsum) - logits[row][tgt] ----------------
__global__ __launch_bounds__(256) void k_loss(const float* __restrict__ rowsum,
                                              const float* __restrict__ logits,
                                              const int* __restrict__ tgt,
                                              float* __restrict__ loss) {
    int row = blockIdx.x * 256 + threadIdx.x;
    float lse = __logf(rowsum[row]);
    float tl = logits[(size_t)row * VOCAB + tgt[row]];
    float c = (lse - tl) * (1.0f / 4096.0f);
    #pragma unroll
    for (int off = 1; off < 64; off <<= 1)
        c += __shfl_xor(c, off);
    __shared__ float ws4[4];
    int lane = threadIdx.x & 63, wave = threadIdx.x >> 6;
    if (lane == 0) ws4[wave] = c;
    __syncthreads();
    if (threadIdx.x == 0)
        atomicAdd(loss, ws4[0] + ws4[1] + ws4[2] + ws4[3]);
}

extern "C" void kernel_launch(void* const* d_in, const int* in_sizes, int n_in,
                              void* d_out, int out_size, void* d_ws, size_t ws_size,
                              hipStream_t stream) {
    (void)in_sizes; (void)n_in; (void)ws_size;
    const int*   idx     = (const int*)d_in[0];
    const int*   targets = (const int*)d_in[1];
    const float* tok     = (const float*)d_in[2];
    const float* pos     = (const float*)d_in[3];
    const float* Wk      = (const float*)d_in[4];
    const float* Wq      = (const float*)d_in[5];
    const float* Wv      = (const float*)d_in[6];
    const float* lmW     = (const float*)d_in[7];
    const float* lmb     = (const float*)d_in[8];

    float* logits = (float*)d_out;
    float* loss   = logits + (size_t)out_size - 1;

    const size_t MB = 1u << 20;
    char* w = (char*)d_ws;
    ushort* Wt3   = (ushort*)(w);                 // 384 KB
    float*  rowsum = (float*)(w + 448 * 1024);    // 16 KB
    ushort* xb    = (ushort*)(w + MB / 2);        // 2 MB
    ushort* qb    = (ushort*)(w + 5 * MB / 2);    // 2 MB
    ushort* kbf   = (ushort*)(w + 9 * MB / 2);    // 2 MB
    ushort* vt    = (ushort*)(w + 13 * MB / 2);   // 2 MB
    ushort* ao    = (ushort*)(w + 17 * MB / 2);   // 2 MB
    ushort* Wt    = (ushort*)(w + 21 * MB / 2);   // 16 MB

    hipMemsetAsync(loss, 0, sizeof(float), stream);
    hipMemsetAsync(rowsum, 0, NROWS * sizeof(float), stream);
    k_pre<<<4288, 256, 0, stream>>>(Wq, Wk, Wv, idx, tok, pos, Wt3, xb);
    k_qkv_mm<<<dim3(NROWS / 128, EMB / 128, 3), 256, 0, stream>>>(xb, Wt3, qb, kbf, vt);
    k_attn_conv<<<4032, 512, 0, stream>>>(qb, kbf, vt, ao, lmW, Wt);
    k_gemm<<<8000, 256, 0, stream>>>(ao, Wt, lmb, logits, rowsum);
    k_loss<<<NROWS / 256, 256, 0, stream>>>(rowsum, logits, targets, loss);
}

// Round 20
// 222.794 us; speedup vs baseline: 1.3048x; 1.3048x over previous
//
#include <hip/hip_runtime.h>
#include <hip/hip_bf16.h>
#include <math.h>

#define VOCAB 32000
#define EMB   256
#define TSEQ  1024
#define NROWS 4096

typedef __attribute__((ext_vector_type(8))) short short8;
typedef __attribute__((ext_vector_type(4))) float f32x4;

static __device__ __forceinline__ unsigned short bfb(float x) {
    __hip_bfloat16 h = __float2bfloat16(x);
    return *(unsigned short*)&h;
}
static __device__ __forceinline__ unsigned pk2(float a, float b) {
    return (unsigned)bfb(a) | ((unsigned)bfb(b) << 16);
}

// ---------------- pre-pass: Wq/Wk/Wv transpose+convert (bx<192), embed (bx>=192) ----------------
__global__ __launch_bounds__(256) void k_pre(const float* __restrict__ Wq,
                                             const float* __restrict__ Wk,
                                             const float* __restrict__ Wv,
                                             const int* __restrict__ idx,
                                             const float* __restrict__ tok,
                                             const float* __restrict__ pos,
                                             ushort* __restrict__ Wt3,
                                             ushort* __restrict__ xb) {
    int bx = blockIdx.x;
    if (bx >= 192) {                       // embed
        int row = bx - 192;
        int t = row & (TSEQ - 1);
        int token = idx[row];
        int e = threadIdx.x;
        xb[row * EMB + e] = bfb(tok[token * EMB + e] + pos[t * EMB + e]);
        return;
    }
    __shared__ float T[32][33];
    int z = bx >> 6, rem = bx & 63;
    const float* W = (z == 0) ? Wq : (z == 1) ? Wk : Wv;
    ushort* out = Wt3 + (size_t)z * EMB * EMB;
    int n0 = (rem >> 3) * 32, k0 = (rem & 7) * 32;
    int tx = threadIdx.x & 31, ty = threadIdx.x >> 5;
    #pragma unroll
    for (int i = 0; i < 4; ++i) {
        int kk = ty + 8 * i;
        T[kk][tx] = W[(size_t)(k0 + kk) * EMB + n0 + tx];
    }
    __syncthreads();
    #pragma unroll
    for (int i = 0; i < 4; ++i) {
        int r = ty + 8 * i;
        out[(size_t)(n0 + r) * EMB + k0 + tx] = bfb(T[tx][r]);
    }
}

// ---------------- qkv MFMA GEMM (unchanged) ----------------
__global__ __launch_bounds__(256) void k_qkv_mm(const ushort* __restrict__ A,
                                                const ushort* __restrict__ Wt3,
                                                ushort* __restrict__ qb,
                                                ushort* __restrict__ kbf,
                                                ushort* __restrict__ vt) {
    __shared__ ushort As[128 * 64];
    __shared__ ushort Bs[128 * 64];

    int z = blockIdx.z;
    const ushort* Bt = Wt3 + (size_t)z * EMB * EMB;

    int m0 = blockIdx.x * 128, n0 = blockIdx.y * 128;
    int tid = threadIdx.x;
    int lane = tid & 63, wave = tid >> 6;
    int wm = wave >> 1, wn = wave & 1;
    int lr = lane >> 3, cc = lane & 7;
    int lrow = lane & 15, lk = lane >> 4;

    f32x4 acc[4][4];
    #pragma unroll
    for (int i = 0; i < 4; ++i)
        #pragma unroll
        for (int j = 0; j < 4; ++j)
            acc[i][j] = (f32x4){0.f, 0.f, 0.f, 0.f};

    for (int k0 = 0; k0 < EMB; k0 += 64) {
        #pragma unroll
        for (int j = 0; j < 4; ++j) {
            int rbase = j * 32 + wave * 8;
            int row = rbase + lr;
            int cs = cc ^ (row & 7);
            const ushort* ga = A + (size_t)(m0 + row) * EMB + k0 + cs * 8;
            const ushort* gb = Bt + (size_t)(n0 + row) * EMB + k0 + cs * 8;
            __builtin_amdgcn_global_load_lds(
                (const __attribute__((address_space(1))) void*)ga,
                (__attribute__((address_space(3))) void*)&As[rbase * 64], 16, 0, 0);
            __builtin_amdgcn_global_load_lds(
                (const __attribute__((address_space(1))) void*)gb,
                (__attribute__((address_space(3))) void*)&Bs[rbase * 64], 16, 0, 0);
        }
        __syncthreads();
        #pragma unroll
        for (int kk = 0; kk < 2; ++kk) {
            short8 a[4], b[4];
            #pragma unroll
            for (int m = 0; m < 4; ++m) {
                int row = wm * 64 + m * 16 + lrow;
                int c2 = (kk * 4 + lk) ^ (row & 7);
                a[m] = *(const short8*)&As[row * 64 + c2 * 8];
            }
            #pragma unroll
            for (int n = 0; n < 4; ++n) {
                int row = wn * 64 + n * 16 + lrow;
                int c2 = (kk * 4 + lk) ^ (row & 7);
                b[n] = *(const short8*)&Bs[row * 64 + c2 * 8];
            }
            if (z < 2) {
                #pragma unroll
                for (int m = 0; m < 4; ++m)
                    #pragma unroll
                    for (int n = 0; n < 4; ++n)
                        acc[m][n] = __builtin_amdgcn_mfma_f32_16x16x32_bf16(
                            b[n], a[m], acc[m][n], 0, 0, 0);   // swapped
            } else {
                #pragma unroll
                for (int m = 0; m < 4; ++m)
                    #pragma unroll
                    for (int n = 0; n < 4; ++n)
                        acc[m][n] = __builtin_amdgcn_mfma_f32_16x16x32_bf16(
                            a[m], b[n], acc[m][n], 0, 0, 0);
            }
        }
        __syncthreads();
    }

    if (z < 2) {
        ushort* out = (z == 0) ? qb : kbf;
        #pragma unroll
        for (int m = 0; m < 4; ++m) {
            int token = m0 + wm * 64 + m * 16 + lrow;
            #pragma unroll
            for (int n = 0; n < 4; ++n) {
                uint2 w;
                w.x = pk2(acc[m][n][0], acc[m][n][1]);
                w.y = pk2(acc[m][n][2], acc[m][n][3]);
                *(uint2*)&out[(size_t)token * EMB + n0 + wn * 64 + n * 16 + lk * 4] = w;
            }
        }
    } else {
        #pragma unroll
        for (int n = 0; n < 4; ++n) {
            int e = n0 + wn * 64 + n * 16 + lrow;
            #pragma unroll
            for (int m = 0; m < 4; ++m) {
                int row = m0 + wm * 64 + m * 16 + lk * 4;
                int bb = row >> 10, rr = row & 1023;
                uint2 w;
                w.x = pk2(acc[m][n][0], acc[m][n][1]);
                w.y = pk2(acc[m][n][2], acc[m][n][3]);
                *(uint2*)&vt[((size_t)bb * EMB + e) * TSEQ + rr] = w;
            }
        }
    }
}

// ---------------- merged: flash attention (blocks 0..31) || lm_W transpose (blocks 32..4031) ----------------
__global__ __launch_bounds__(512) void k_attn_conv(const ushort* __restrict__ qg,
                                                   const ushort* __restrict__ kg,
                                                   const ushort* __restrict__ vt,
                                                   ushort* __restrict__ ao,
                                                   const float* __restrict__ lmW,
                                                   ushort* __restrict__ Wt) {
    __shared__ ushort K_s[2][32 * 256];
    __shared__ ushort V_s[2][256 * 32];

    if (blockIdx.x >= 32) {
        int t = threadIdx.x & 255;
        int half = threadIdx.x >> 8;
        int tile = (blockIdx.x - 32) * 2 + half;
        int n0 = (tile >> 3) * 32, k0 = (tile & 7) * 32;
        float* T = (float*)&K_s[0][0] + half * (32 * 33);
        int tx = t & 31, ty = t >> 5;
        #pragma unroll
        for (int i = 0; i < 4; ++i) {
            int kk = ty + 8 * i;
            T[kk * 33 + tx] = lmW[(size_t)(k0 + kk) * VOCAB + n0 + tx];
        }
        __syncthreads();
        #pragma unroll
        for (int i = 0; i < 4; ++i) {
            int r = ty + 8 * i;
            Wt[(size_t)(n0 + r) * EMB + k0 + tx] = bfb(T[tx * 33 + r]);
        }
        return;
    }

    int b = blockIdx.x >> 3;
    int g = blockIdx.x & 7;
    int wave = threadIdx.x >> 6;
    int lane = threadIdx.x & 63;
    int qbase = g * 128 + wave * 16;
    int q = lane & 15, lk = lane >> 4;

    const ushort* qrow = qg + (size_t)(b * TSEQ + qbase + q) * EMB;
    short8 qf[8];
    #pragma unroll
    for (int c = 0; c < 8; ++c)
        qf[c] = *(const short8*)&qrow[c * 32 + lk * 8];

    f32x4 o[16];
    #pragma unroll
    for (int i = 0; i < 16; ++i) o[i] = (f32x4){0.f, 0.f, 0.f, 0.f};
    float m_run = -1e30f, l_run = 0.f;

    auto STAGE = [&](int buf, int st) {
        const ushort* kbase = kg + (size_t)(b * TSEQ + st * 32) * EMB;
        #pragma unroll
        for (int i = 0; i < 2; ++i) {
            int t = wave * 2 + i;
            int r = t * 2 + (lane >> 5);
            int slot = lane & 31;
            int chunk = slot ^ (r & 7);
            const ushort* src = kbase + r * EMB + chunk * 8;
            __builtin_amdgcn_global_load_lds(
                (const __attribute__((address_space(1))) void*)src,
                (__attribute__((address_space(3))) void*)&K_s[buf][t * 512], 16, 0, 0);
        }
        #pragma unroll
        for (int i = 0; i < 2; ++i) {
            int t = wave * 2 + i;
            int e = t * 16 + (lane >> 2);
            int slot = lane & 3;
            int chunk = slot ^ (e & 3);
            const ushort* src = vt + ((size_t)b * EMB + e) * TSEQ + st * 32 + chunk * 8;
            __builtin_amdgcn_global_load_lds(
                (const __attribute__((address_space(1))) void*)src,
                (__attribute__((address_space(3))) void*)&V_s[buf][t * 512], 16, 0, 0);
        }
    };

    int wlast = (qbase + 15) >> 5;
    int glast = (g * 128 + 127) >> 5;
    STAGE(0, 0);
    int buf = 0;

    for (int st = 0; st <= glast; ++st) {
        if (st < glast) {
            STAGE(buf ^ 1, st + 1);
            asm volatile("s_waitcnt vmcnt(4)" ::: "memory");
        } else {
            asm volatile("s_waitcnt vmcnt(0)" ::: "memory");
        }
        __builtin_amdgcn_s_barrier();

        if (st <= wlast) {
            f32x4 sa0 = (f32x4){0.f, 0.f, 0.f, 0.f};
            f32x4 sa1 = (f32x4){0.f, 0.f, 0.f, 0.f};
            #pragma unroll
            for (int c = 0; c < 8; ++c) {
                int sl = (c * 4 + lk) ^ (q & 7);
                short8 kf0 = *(const short8*)&K_s[buf][q * 256 + sl * 8];
                short8 kf1 = *(const short8*)&K_s[buf][(16 + q) * 256 + sl * 8];
                sa0 = __builtin_amdgcn_mfma_f32_16x16x32_bf16(kf0, qf[c], sa0, 0, 0, 0);
                sa1 = __builtin_amdgcn_mfma_f32_16x16x32_bf16(kf1, qf[c], sa1, 0, 0, 0);
            }

            float sv0[4], sv1[4];
            #pragma unroll
            for (int j = 0; j < 4; ++j) { sv0[j] = sa0[j] * 0.0625f; sv1[j] = sa1[j] * 0.0625f; }
            if (st == wlast) {
                int qgl = qbase + q;
                #pragma unroll
                for (int j = 0; j < 4; ++j) {
                    if (st * 32 + lk * 4 + j > qgl)      sv0[j] = -1e30f;
                    if (st * 32 + 16 + lk * 4 + j > qgl) sv1[j] = -1e30f;
                }
            }

            float tm = sv0[0];
            #pragma unroll
            for (int j = 1; j < 4; ++j) tm = fmaxf(tm, sv0[j]);
            #pragma unroll
            for (int j = 0; j < 4; ++j) tm = fmaxf(tm, sv1[j]);
            tm = fmaxf(tm, __shfl_xor(tm, 16));
            tm = fmaxf(tm, __shfl_xor(tm, 32));
            float mn = fmaxf(m_run, tm);
            float alpha = __expf(m_run - mn);
            float p0[4], p1[4], ts = 0.f;
            #pragma unroll
            for (int j = 0; j < 4; ++j) {
                p0[j] = __expf(sv0[j] - mn);
                p1[j] = __expf(sv1[j] - mn);
                ts += p0[j] + p1[j];
            }
            ts += __shfl_xor(ts, 16);
            ts += __shfl_xor(ts, 32);
            l_run = l_run * alpha + ts;
            m_run = mn;

            #pragma unroll
            for (int i = 0; i < 16; ++i) {
                o[i][0] *= alpha; o[i][1] *= alpha; o[i][2] *= alpha; o[i][3] *= alpha;
            }

            unsigned c0 = pk2(p0[0], p0[1]), c1 = pk2(p0[2], p0[3]);
            unsigned d0 = pk2(p1[0], p1[1]), d1 = pk2(p1[2], p1[3]);
            int sA = q + 32 * (lk & 1);
            int sB = sA + 16;
            unsigned a0c = __shfl(c0, sA), a1c = __shfl(c1, sA);
            unsigned b0c = __shfl(c0, sB), b1c = __shfl(c1, sB);
            unsigned a0d = __shfl(d0, sA), a1d = __shfl(d1, sA);
            unsigned b0d = __shfl(d0, sB), b1d = __shfl(d1, sB);
            bool hi = (lk >> 1) != 0;
            union { short8 s; unsigned u[4]; } pb;
            pb.u[0] = hi ? a0d : a0c;
            pb.u[1] = hi ? a1d : a1c;
            pb.u[2] = hi ? b0d : b0c;
            pb.u[3] = hi ? b1d : b1c;

            #pragma unroll
            for (int eb = 0; eb < 16; ++eb) {
                int er = eb * 16 + q;
                int sl = lk ^ (er & 3);
                short8 vf = *(const short8*)&V_s[buf][er * 32 + sl * 8];
                o[eb] = __builtin_amdgcn_mfma_f32_16x16x32_bf16(vf, pb.s, o[eb], 0, 0, 0);
            }
        }
        __builtin_amdgcn_s_barrier();
        buf ^= 1;
    }

    float inv_l = 1.f / l_run;
    ushort* orow = ao + (size_t)(b * TSEQ + qbase + q) * EMB;
    #pragma unroll
    for (int eb = 0; eb < 16; ++eb) {
        uint2 w;
        w.x = pk2(o[eb][0] * inv_l, o[eb][1] * inv_l);
        w.y = pk2(o[eb][2] * inv_l, o[eb][3] * inv_l);
        *(uint2*)&orow[eb * 16 + lk * 4] = w;
    }
}

// ---------------- logits GEMM: R18 config (m0-inner swizzle, LDS-coalesced nt epilogue) ----------------
__global__ __launch_bounds__(256) void k_gemm(const ushort* __restrict__ A,
                                              const ushort* __restrict__ Bt,
                                              const float* __restrict__ lmb,
                                              float* __restrict__ C,
                                              float* __restrict__ rowsum) {
    __shared__ ushort SH[4 * 128 * 64];   // 64 KB: As[0],As[1],Bs[0],Bs[1]; reused as C-tile

    int linear = blockIdx.x;
    int swz = (linear & 7) * 1000 + (linear >> 3);   // bijective XCD swizzle (8000%8==0)
    int m0 = (swz & 31) * 128;                        // m0 INNER (R18-proven: B-panel L2 reuse)
    int nb = swz >> 5;
    int n0 = nb * 128;

    int tid = threadIdx.x;
    int lane = tid & 63, wave = tid >> 6;
    int wm = wave >> 1, wn = wave & 1;
    int lr = lane >> 3, cc = lane & 7;
    int lrow = lane & 15, lk = lane >> 4;

    auto STAGE = [&](int bufi, int k0) {
        ushort* Asb = &SH[bufi * 8192];
        ushort* Bsb = &SH[16384 + bufi * 8192];
        #pragma unroll
        for (int j = 0; j < 4; ++j) {
            int rbase = j * 32 + wave * 8;
            int row = rbase + lr;
            int cs = cc ^ (row & 7);
            const ushort* ga = A + (size_t)(m0 + row) * EMB + k0 + cs * 8;
            const ushort* gb = Bt + (size_t)(n0 + row) * EMB + k0 + cs * 8;
            __builtin_amdgcn_global_load_lds(
                (const __attribute__((address_space(1))) void*)ga,
                (__attribute__((address_space(3))) void*)&Asb[rbase * 64], 16, 0, 0);
            __builtin_amdgcn_global_load_lds(
                (const __attribute__((address_space(1))) void*)gb,
                (__attribute__((address_space(3))) void*)&Bsb[rbase * 64], 16, 0, 0);
        }
    };

    f32x4 acc[4][4];
    #pragma unroll
    for (int i = 0; i < 4; ++i)
        #pragma unroll
        for (int j = 0; j < 4; ++j)
            acc[i][j] = (f32x4){0.f, 0.f, 0.f, 0.f};

    STAGE(0, 0);
    asm volatile("s_waitcnt vmcnt(0)" ::: "memory");
    __syncthreads();

    #pragma unroll
    for (int t = 0; t < 4; ++t) {
        if (t < 3) STAGE((t + 1) & 1, (t + 1) * 64);   // prefetch next, in flight under compute
        const ushort* Ab = &SH[(t & 1) * 8192];
        const ushort* Bb = &SH[16384 + (t & 1) * 8192];
        #pragma unroll
        for (int kk = 0; kk < 2; ++kk) {
            short8 a[4], b[4];
            #pragma unroll
            for (int m = 0; m < 4; ++m) {
                int row = wm * 64 + m * 16 + lrow;
                int c2 = (kk * 4 + lk) ^ (row & 7);
                a[m] = *(const short8*)&Ab[row * 64 + c2 * 8];
            }
            #pragma unroll
            for (int n = 0; n < 4; ++n) {
                int row = wn * 64 + n * 16 + lrow;
                int c2 = (kk * 4 + lk) ^ (row & 7);
                b[n] = *(const short8*)&Bb[row * 64 + c2 * 8];
            }
            #pragma unroll
            for (int m = 0; m < 4; ++m)
                #pragma unroll
                for (int n = 0; n < 4; ++n)
                    acc[m][n] = __builtin_amdgcn_mfma_f32_16x16x32_bf16(
                        b[n], a[m], acc[m][n], 0, 0, 0);   // SWAPPED
        }
        if (t < 3) {
            asm volatile("s_waitcnt vmcnt(0)" ::: "memory");
            __syncthreads();
        }
    }

    // bias: 4 consecutive vocab cols per lane per n
    f32x4 bias4[4];
    #pragma unroll
    for (int n = 0; n < 4; ++n)
        bias4[n] = *(const f32x4*)&lmb[n0 + wn * 64 + n * 16 + lk * 4];

    // per-token sum-exp over this wn-half's 64 cols -> atomic into L2-resident rowsum
    #pragma unroll
    for (int m = 0; m < 4; ++m) {
        float tS = 0.f;
        #pragma unroll
        for (int n = 0; n < 4; ++n)
            #pragma unroll
            for (int j = 0; j < 4; ++j)
                tS += __expf(acc[m][n][j] + bias4[n][j]);
        tS += __shfl_xor(tS, 16);
        tS += __shfl_xor(tS, 32);
        if (lk == 0)
            atomicAdd(&rowsum[m0 + wm * 64 + m * 16 + lrow], tS);
    }

    // ---- LDS-coalesced C write (R18: +45us vs scattered 64B chunks) ----
    __syncthreads();                      // all waves done reading As/Bs for MFMA
    f32x4* Cs4 = (f32x4*)SH;              // 128 tokens x 32 chunks (16B each)
    #pragma unroll
    for (int m = 0; m < 4; ++m) {
        int ltok = wm * 64 + m * 16 + lrow;
        #pragma unroll
        for (int n = 0; n < 4; ++n) {
            int cq = wn * 16 + n * 4 + lk;
            Cs4[ltok * 32 + (cq ^ ((ltok & 7) << 2))] = acc[m][n] + bias4[n];
        }
    }
    __syncthreads();                      // C-tile complete
    int lt_base = tid >> 5;
    int cq_out = tid & 31;
    #pragma unroll
    for (int it = 0; it < 16; ++it) {
        int lt = it * 8 + lt_base;
        f32x4 v = Cs4[lt * 32 + (cq_out ^ ((lt & 7) << 2))];
        __builtin_nontemporal_store(v,
            (f32x4*)&C[(size_t)(m0 + lt) * VOCAB + n0 + cq_out * 4]);
    }
}

// ---------------- loss: 16 blocks, log(rowsum) - logits[row][tgt] ----------------
__global__ __launch_bounds__(256) void k_loss(const float* __restrict__ rowsum,
                                              const float* __restrict__ logits,
                                              const int* __restrict__ tgt,
                                              float* __restrict__ loss) {
    int row = blockIdx.x * 256 + threadIdx.x;
    float lse = __logf(rowsum[row]);
    float tl = logits[(size_t)row * VOCAB + tgt[row]];
    float c = (lse - tl) * (1.0f / 4096.0f);
    #pragma unroll
    for (int off = 1; off < 64; off <<= 1)
        c += __shfl_xor(c, off);
    __shared__ float ws4[4];
    int lane = threadIdx.x & 63, wave = threadIdx.x >> 6;
    if (lane == 0) ws4[wave] = c;
    __syncthreads();
    if (threadIdx.x == 0)
        atomicAdd(loss, ws4[0] + ws4[1] + ws4[2] + ws4[3]);
}

extern "C" void kernel_launch(void* const* d_in, const int* in_sizes, int n_in,
                              void* d_out, int out_size, void* d_ws, size_t ws_size,
                              hipStream_t stream) {
    (void)in_sizes; (void)n_in; (void)ws_size;
    const int*   idx     = (const int*)d_in[0];
    const int*   targets = (const int*)d_in[1];
    const float* tok     = (const float*)d_in[2];
    const float* pos     = (const float*)d_in[3];
    const float* Wk      = (const float*)d_in[4];
    const float* Wq      = (const float*)d_in[5];
    const float* Wv      = (const float*)d_in[6];
    const float* lmW     = (const float*)d_in[7];
    const float* lmb     = (const float*)d_in[8];

    float* logits = (float*)d_out;
    float* loss   = logits + (size_t)out_size - 1;

    const size_t MB = 1u << 20;
    char* w = (char*)d_ws;
    ushort* Wt3   = (ushort*)(w);                 // 384 KB
    float*  rowsum = (float*)(w + 448 * 1024);    // 16 KB
    ushort* xb    = (ushort*)(w + MB / 2);        // 2 MB
    ushort* qb    = (ushort*)(w + 5 * MB / 2);    // 2 MB
    ushort* kbf   = (ushort*)(w + 9 * MB / 2);    // 2 MB
    ushort* vt    = (ushort*)(w + 13 * MB / 2);   // 2 MB
    ushort* ao    = (ushort*)(w + 17 * MB / 2);   // 2 MB
    ushort* Wt    = (ushort*)(w + 21 * MB / 2);   // 16 MB

    hipMemsetAsync(loss, 0, sizeof(float), stream);
    hipMemsetAsync(rowsum, 0, NROWS * sizeof(float), stream);
    k_pre<<<4288, 256, 0, stream>>>(Wq, Wk, Wv, idx, tok, pos, Wt3, xb);
    k_qkv_mm<<<dim3(NROWS / 128, EMB / 128, 3), 256, 0, stream>>>(xb, Wt3, qb, kbf, vt);
    k_attn_conv<<<4032, 512, 0, stream>>>(qb, kbf, vt, ao, lmW, Wt);
    k_gemm<<<8000, 256, 0, stream>>>(ao, Wt, lmb, logits, rowsum);
    k_loss<<<NROWS / 256, 256, 0, stream>>>(rowsum, logits, targets, loss);
}